// Round 3
// baseline (261.431 us; speedup 1.0000x reference)
//
#include <hip/hip_runtime.h>
#include <math.h>

#define B_     2
#define C_     64
#define N_     20000
#define K_     16
#define COUT_  64
#define NSLICE 8
#define SCH    8                       // channels per slice (8 x 8 = 64)
#define TN1    32                      // stage1 nodes per block
#define NB1    (N_ / TN1)              // 625 (exact)
#define TN2    128                     // stage2 nodes per block (4 waves x 32)
#define NB2    ((N_ + TN2 - 1) / TN2)  // 157

static __device__ __forceinline__ unsigned short f2bf(float f) {
    union { float f; unsigned u; } v; v.f = f;
    unsigned r = (v.u + 0x7FFFu + ((v.u >> 16) & 1u)) >> 16;  // RNE
    return (unsigned short)r;
}

// ---------------------------------------------------------------------------
// Stage 1: per-node linear transforms (z = (W1-W2)x + b, y = W2 x) stored as
// bf16 in slice-major layout [b][slice][n][8ch], PLUS edge prep: pack
// (i0,i1) into one uint and precompute fp32 suppression s = 2*sigmoid(-dis).
// lane = output channel o; weights in per-lane registers.
// ---------------------------------------------------------------------------
__global__ __launch_bounds__(256, 2)
void stage1(const float* __restrict__ x, const int* __restrict__ ei,
            const float* __restrict__ pos, const float* __restrict__ W,
            const float* __restrict__ bias,
            unsigned short* __restrict__ zbuf, unsigned short* __restrict__ ybuf,
            unsigned int* __restrict__ pk, float* __restrict__ sup) {
    __shared__ float xt[TN1][68];   // transposed x tile, 16B-aligned rows

    const int bi   = blockIdx.x;
    const int b    = bi / NB1;
    const int n0   = (bi % NB1) * TN1;
    const int t    = threadIdx.x;
    const int lane = t & 63;        // = output channel o
    const int w    = t >> 6;

    // ---- stage x tile into LDS transposed (coalesced global reads) ----
    const float* xb = x + (size_t)b * C_ * N_;
    #pragma unroll
    for (int r = 0; r < 8; ++r) {
        int flat = r * 256 + t;     // 2048 = 64c x 32n
        int c  = flat >> 5;
        int nl = flat & 31;
        xt[nl][c] = xb[c * N_ + n0 + nl];   // N_%TN1==0: no tail
    }

    // ---- per-lane weight rows ----
    float wz[64], wy[64];
    const float* wrow = W + lane * (2 * C_);
    #pragma unroll
    for (int c4 = 0; c4 < 16; ++c4) {
        float4 w1 = *(const float4*)&wrow[c4 * 4];
        float4 w2 = *(const float4*)&wrow[64 + c4 * 4];
        wz[4*c4+0] = w1.x - w2.x;  wy[4*c4+0] = w2.x;
        wz[4*c4+1] = w1.y - w2.y;  wy[4*c4+1] = w2.y;
        wz[4*c4+2] = w1.z - w2.z;  wy[4*c4+2] = w2.z;
        wz[4*c4+3] = w1.w - w2.w;  wy[4*c4+3] = w2.w;
    }
    const float bo = bias[lane];

    __syncthreads();

    // ---- each wave computes 8 nodes ----
    const int sl  = lane >> 3;      // this lane's slice
    const int c8  = lane & 7;       // channel within slice
    #pragma unroll 1
    for (int j = 0; j < 8; ++j) {
        int nl = w * 8 + j;
        int n  = n0 + nl;
        float z = bo, y = 0.0f;
        #pragma unroll
        for (int c4 = 0; c4 < 16; ++c4) {
            float4 xv = *(const float4*)&xt[nl][c4 * 4];   // wave-uniform broadcast
            z = fmaf(wz[4*c4+0], xv.x, z);  y = fmaf(wy[4*c4+0], xv.x, y);
            z = fmaf(wz[4*c4+1], xv.y, z);  y = fmaf(wy[4*c4+1], xv.y, y);
            z = fmaf(wz[4*c4+2], xv.z, z);  y = fmaf(wy[4*c4+2], xv.z, y);
            z = fmaf(wz[4*c4+3], xv.w, z);  y = fmaf(wy[4*c4+3], xv.w, y);
        }
        size_t off = ((size_t)(b * NSLICE + sl) * N_ + n) * SCH + c8;
        zbuf[off] = f2bf(z);
        ybuf[off] = f2bf(y);
    }

    // ---- edge prep for this tile's 512 edges ----
    const int*   e0 = ei + (size_t)b * N_ * K_;
    const int*   e1 = ei + ((size_t)B_ + b) * N_ * K_;
    const float* pb = pos + (size_t)b * 3 * N_;
    #pragma unroll
    for (int i = 0; i < 2; ++i) {
        int idx = n0 * K_ + i * 256 + t;      // coalesced
        int i0 = e0[idx];
        int i1 = e1[idx];
        float dx = pb[i0]          - pb[i1];
        float dy = pb[N_ + i0]     - pb[N_ + i1];
        float dz = pb[2*N_ + i0]   - pb[2*N_ + i1];
        float dis = sqrtf(dx*dx + dy*dy + dz*dz);
        float s = 2.0f / (1.0f + __expf(dis));          // 2*sigmoid(-dis)
        pk [(size_t)b * N_ * K_ + idx] = (unsigned)i0 | ((unsigned)i1 << 16);
        sup[(size_t)b * N_ * K_ + idx] = s;
    }
}

// ---------------------------------------------------------------------------
// Stage 2: per-edge combine + max over K, channel-sliced.
// slice = blockIdx % 8 -> (heuristic) pins each slice's 1.28 MB z/y working
// set in one XCD's L2. lane = (k = lane>>2, chpair = lane&3): all 16 edges of
// a node processed in parallel, ushort2 bf16 gathers, shfl_xor max-reduce.
// ---------------------------------------------------------------------------
__global__ __launch_bounds__(256, 4)
void stage2(const unsigned int* __restrict__ pk, const float* __restrict__ sup,
            const unsigned short* __restrict__ zbuf,
            const unsigned short* __restrict__ ybuf,
            float* __restrict__ out) {
    __shared__ float tile[4][SCH][32];   // [wave][ch][node]

    const int bi = blockIdx.x;
    const int s  = bi & 7;               // slice -> XCD via %8 round-robin
    const int r  = bi >> 3;
    const int b  = r / NB2;
    const int n0 = (r % NB2) * TN2;
    const int t    = threadIdx.x;
    const int lane = t & 63;
    const int w    = t >> 6;
    const int k    = lane >> 2;          // edge 0..15
    const int cq   = lane & 3;           // channel pair 0..3

    const unsigned int*   pkb  = pk  + (size_t)b * N_ * K_;
    const float*          supb = sup + (size_t)b * N_ * K_;
    const unsigned short* zb   = zbuf + (size_t)(b * NSLICE + s) * N_ * SCH;
    const unsigned short* yb   = ybuf + (size_t)(b * NSLICE + s) * N_ * SCH;

    #pragma unroll 1
    for (int j = 0; j < 32; ++j) {
        int n = n0 + w * 32 + j;         // wave-uniform
        float v0 = 0.0f, v1 = 0.0f;
        if (n < N_) {
            unsigned p  = pkb [n * K_ + k];   // quad-broadcast
            float    sk = supb[n * K_ + k];
            int i0 = (int)(p & 0xFFFFu);
            int i1 = (int)(p >> 16);
            unsigned zz = *(const unsigned int*)(zb + i1 * SCH + cq * 2);
            unsigned yy = *(const unsigned int*)(yb + i0 * SCH + cq * 2);
            union { unsigned u; float f; } za, zc, ya, yc;
            za.u = zz << 16; zc.u = zz & 0xFFFF0000u;
            ya.u = yy << 16; yc.u = yy & 0xFFFF0000u;
            v0 = fmaxf(za.f + ya.f, 0.0f) * sk;
            v1 = fmaxf(zc.f + yc.f, 0.0f) * sk;
        }
        // max over the 16 edges (xor strides 4..32 preserve cq class)
        #pragma unroll
        for (int st = 4; st < 64; st <<= 1) {
            v0 = fmaxf(v0, __shfl_xor(v0, st));
            v1 = fmaxf(v1, __shfl_xor(v1, st));
        }
        if (lane < 4) {                  // cq == lane
            tile[w][2*cq    ][j] = v0;
            tile[w][2*cq + 1][j] = v1;
        }
    }

    __syncthreads();

    // coalesced writeback: 8 ch x 128 nodes
    #pragma unroll
    for (int r2 = 0; r2 < 4; ++r2) {
        int flat = r2 * 256 + t;         // 1024 = 8ch x 128n
        int ch  = flat >> 7;
        int col = flat & 127;
        int n   = n0 + col;
        if (n < N_)
            out[((size_t)b * COUT_ + s * SCH + ch) * N_ + n] =
                tile[col >> 5][ch][col & 31];
    }
}

// ---------------------------------------------------------------------------
extern "C" void kernel_launch(void* const* d_in, const int* in_sizes, int n_in,
                              void* d_out, int out_size, void* d_ws, size_t ws_size,
                              hipStream_t stream) {
    const float* x    = (const float*)d_in[0];   // [B, C, N, 1]
    const int*   ei   = (const int*)  d_in[1];   // [2, B, N, K]
    const float* pos  = (const float*)d_in[2];   // [B, 3, N, 1]
    const float* W    = (const float*)d_in[3];   // [COUT, 2C]
    const float* bias = (const float*)d_in[4];   // [COUT]
    float*       out  = (float*)d_out;           // [B, COUT, N, 1]

    const size_t tabElems = (size_t)B_ * NSLICE * N_ * SCH;  // 2.56M ushorts
    unsigned short* zbuf = (unsigned short*)d_ws;
    unsigned short* ybuf = zbuf + tabElems;
    unsigned int*   pk   = (unsigned int*)(ybuf + tabElems);         // 4B-aligned
    float*          sup  = (float*)(pk + (size_t)B_ * N_ * K_);

    hipLaunchKernelGGL(stage1, dim3(B_ * NB1), dim3(256), 0, stream,
                       x, ei, pos, W, bias, zbuf, ybuf, pk, sup);
    hipLaunchKernelGGL(stage2, dim3(NB2 * B_ * NSLICE), dim3(256), 0, stream,
                       pk, sup, zbuf, ybuf, out);
}